// Round 10
// baseline (164.531 us; speedup 1.0000x reference)
//
#include <hip/hip_runtime.h>

// RNN: h_{t+1} = relu(x_t*W_ih^T + b_ih + b_hh + W_hh·h_t), out = fc(h_T).
// B=4096, T=1000, H=20.  16 lanes per batch, 1024 waves = 1 per SIMD.
//
// Alternating-role scheme (R6+): lane (a,bq) of each 16-lane group:
//   EVEN step: rows a-group x k-slice bq; reduce over bq = quad_perm butterfly.
//   ODD  step: rows bq-group x k-slice a; reduce over a = row_ror:4/8 folds.
// R9: 20-step block prefetch of the x stream fixed the load-latency stall
// (140 -> 102 us, VALUBusy 52 -> 77%).
//
// R9 residual: busy cycles ~ 65-80 insts/step, not the nominal 55 -> the
// update_dpp(0,..)+add folds likely compile to mov0+mov_dpp+add (3 insts per
// fold element = 30 insts of fold instead of 10). This version hand-fuses
// each fold element into ONE v_add_f32_dpp via inline asm:
//   a = dpp(a) + a   (dst=src1=a, dpp on src0)
// Step = 5 init-fma + 25 fma + 10 v_add_f32_dpp + 5 v_max = 45 insts.
// Hazards: every dpp source register was written >=4 insts earlier (k-major
// order), so no DPP-read-after-VALU-write wait states are needed.

#define TT 1000

struct F5 { float v0, v1, v2, v3, v4; };

#define PIN(v) asm volatile("" : "+v"(v))
__device__ __forceinline__ void pin5(F5& f) {
    PIN(f.v0); PIN(f.v1); PIN(f.v2); PIN(f.v3); PIN(f.v4);
}
__device__ __forceinline__ void keep5(const F5& f) {
    asm volatile("" :: "v"(f.v0), "v"(f.v1), "v"(f.v2), "v"(f.v3), "v"(f.v4));
}

// fused fold: a = dpp(a) + a, one instruction
#define FOLD_QP1(a)  asm volatile("v_add_f32_dpp %0, %1, %0 quad_perm:[1,0,3,2] row_mask:0xf bank_mask:0xf" : "+v"(a) : "v"(a))
#define FOLD_QP2(a)  asm volatile("v_add_f32_dpp %0, %1, %0 quad_perm:[2,3,0,1] row_mask:0xf bank_mask:0xf" : "+v"(a) : "v"(a))
#define FOLD_ROR4(a) asm volatile("v_add_f32_dpp %0, %1, %0 row_ror:4 row_mask:0xf bank_mask:0xf" : "+v"(a) : "v"(a))
#define FOLD_ROR8(a) asm volatile("v_add_f32_dpp %0, %1, %0 row_ror:8 row_mask:0xf bank_mask:0xf" : "+v"(a) : "v"(a))

// One timestep, breadth-first, column-major tile (wck.vj = W[row j][col k]).
template <bool EVEN>
__device__ __forceinline__ void step(float xt, F5& h,
                                     const F5& wc0, const F5& wc1,
                                     const F5& wc2, const F5& wc3,
                                     const F5& wc4,
                                     const F5& wih, const F5& bias) {
    float a0 = __builtin_fmaf(xt, wih.v0, bias.v0);
    float a1 = __builtin_fmaf(xt, wih.v1, bias.v1);
    float a2 = __builtin_fmaf(xt, wih.v2, bias.v2);
    float a3 = __builtin_fmaf(xt, wih.v3, bias.v3);
    float a4 = __builtin_fmaf(xt, wih.v4, bias.v4);

#define KCOL(hk, wc)                              \
    a0 = __builtin_fmaf(hk, (wc).v0, a0);         \
    a1 = __builtin_fmaf(hk, (wc).v1, a1);         \
    a2 = __builtin_fmaf(hk, (wc).v2, a2);         \
    a3 = __builtin_fmaf(hk, (wc).v3, a3);         \
    a4 = __builtin_fmaf(hk, (wc).v4, a4);
    KCOL(h.v0, wc0) KCOL(h.v1, wc1) KCOL(h.v2, wc2) KCOL(h.v3, wc3) KCOL(h.v4, wc4)
#undef KCOL

    if constexpr (EVEN) {
        FOLD_QP1(a0); FOLD_QP1(a1); FOLD_QP1(a2); FOLD_QP1(a3); FOLD_QP1(a4);
        FOLD_QP2(a0); FOLD_QP2(a1); FOLD_QP2(a2); FOLD_QP2(a3); FOLD_QP2(a4);
    } else {
        FOLD_ROR4(a0); FOLD_ROR4(a1); FOLD_ROR4(a2); FOLD_ROR4(a3); FOLD_ROR4(a4);
        FOLD_ROR8(a0); FOLD_ROR8(a1); FOLD_ROR8(a2); FOLD_ROR8(a3); FOLD_ROR8(a4);
    }

    h.v0 = fmaxf(a0, 0.f); h.v1 = fmaxf(a1, 0.f); h.v2 = fmaxf(a2, 0.f);
    h.v3 = fmaxf(a3, 0.f); h.v4 = fmaxf(a4, 0.f);
}

__global__ void
__attribute__((amdgpu_flat_work_group_size(64, 64), amdgpu_waves_per_eu(1, 1)))
rnn_fused_kernel(const float* __restrict__ x,
                 const float* __restrict__ W_ih,
                 const float* __restrict__ W_hh,
                 const float* __restrict__ b_ih,
                 const float* __restrict__ b_hh,
                 const float* __restrict__ fc_w,
                 const float* __restrict__ fc_b,
                 float* __restrict__ out) {
    const int tid = blockIdx.x * 64 + threadIdx.x;
    const int b   = tid >> 4;     // batch element
    const int gl  = tid & 15;     // lane in 16-lane group
    const int a   = gl >> 2;      // quad index
    const int bq  = gl & 3;       // position in quad

    // --- weight tiles, column-major
    F5 we0, we1, we2, we3, we4;   // wek.vj = W[a*5+j][bq*5+k]
    F5 wo0, wo1, wo2, wo3, wo4;   // wok.vj = W[bq*5+j][a*5+k]
#define LOADC(wk, k, rbase, cbase)                                           \
    { (wk).v0 = W_hh[((rbase) + 0) * 20 + (cbase) + (k)];                    \
      (wk).v1 = W_hh[((rbase) + 1) * 20 + (cbase) + (k)];                    \
      (wk).v2 = W_hh[((rbase) + 2) * 20 + (cbase) + (k)];                    \
      (wk).v3 = W_hh[((rbase) + 3) * 20 + (cbase) + (k)];                    \
      (wk).v4 = W_hh[((rbase) + 4) * 20 + (cbase) + (k)]; }
    LOADC(we0, 0, a * 5, bq * 5) LOADC(we1, 1, a * 5, bq * 5)
    LOADC(we2, 2, a * 5, bq * 5) LOADC(we3, 3, a * 5, bq * 5)
    LOADC(we4, 4, a * 5, bq * 5)
    LOADC(wo0, 0, bq * 5, a * 5) LOADC(wo1, 1, bq * 5, a * 5)
    LOADC(wo2, 2, bq * 5, a * 5) LOADC(wo3, 3, bq * 5, a * 5)
    LOADC(wo4, 4, bq * 5, a * 5)
#undef LOADC

    const bool eact = (bq == 0);
    const bool oact = (a == 0);
    F5 wie, bie, wio, bio;
    {
        const float* pw = W_ih + a * 5;
        const float* p1 = b_ih + a * 5;
        const float* p2 = b_hh + a * 5;
        wie.v0 = eact ? pw[0] : 0.f;  bie.v0 = eact ? (p1[0] + p2[0]) : 0.f;
        wie.v1 = eact ? pw[1] : 0.f;  bie.v1 = eact ? (p1[1] + p2[1]) : 0.f;
        wie.v2 = eact ? pw[2] : 0.f;  bie.v2 = eact ? (p1[2] + p2[2]) : 0.f;
        wie.v3 = eact ? pw[3] : 0.f;  bie.v3 = eact ? (p1[3] + p2[3]) : 0.f;
        wie.v4 = eact ? pw[4] : 0.f;  bie.v4 = eact ? (p1[4] + p2[4]) : 0.f;
    }
    {
        const float* pw = W_ih + bq * 5;
        const float* p1 = b_ih + bq * 5;
        const float* p2 = b_hh + bq * 5;
        wio.v0 = oact ? pw[0] : 0.f;  bio.v0 = oact ? (p1[0] + p2[0]) : 0.f;
        wio.v1 = oact ? pw[1] : 0.f;  bio.v1 = oact ? (p1[1] + p2[1]) : 0.f;
        wio.v2 = oact ? pw[2] : 0.f;  bio.v2 = oact ? (p1[2] + p2[2]) : 0.f;
        wio.v3 = oact ? pw[3] : 0.f;  bio.v3 = oact ? (p1[3] + p2[3]) : 0.f;
        wio.v4 = oact ? pw[4] : 0.f;  bio.v4 = oact ? (p1[4] + p2[4]) : 0.f;
    }

    pin5(we0); pin5(we1); pin5(we2); pin5(we3); pin5(we4);
    pin5(wo0); pin5(wo1); pin5(wo2); pin5(wo3); pin5(wo4);
    pin5(wie); pin5(bie); pin5(wio); pin5(bio);

    F5 h = {0.f, 0.f, 0.f, 0.f, 0.f};

    const float* __restrict__ xb = x + (size_t)b * TT;

    // --- 20-step register blocks, double-buffered (R9 structure, kept)
#define LOAD5(P0, P1, P2, P3, P4, off)                  \
    P0 = *(const float4*)(xb + (off));                  \
    P1 = *(const float4*)(xb + (off) + 4);              \
    P2 = *(const float4*)(xb + (off) + 8);              \
    P3 = *(const float4*)(xb + (off) + 12);             \
    P4 = *(const float4*)(xb + (off) + 16);

#define STEP_E(xv) step<true >(xv, h, we0, we1, we2, we3, we4, wie, bie);
#define STEP_O(xv) step<false>(xv, h, wo0, wo1, wo2, wo3, wo4, wio, bio);
#define RUN4(Q)  STEP_E(Q.x) STEP_O(Q.y) STEP_E(Q.z) STEP_O(Q.w)
#define RUN20(P0, P1, P2, P3, P4) RUN4(P0) RUN4(P1) RUN4(P2) RUN4(P3) RUN4(P4)

    float4 A0, A1, A2, A3, A4, B0, B1, B2, B3, B4;
    LOAD5(A0, A1, A2, A3, A4, 0)    // block 0: steps 0..19
    LOAD5(B0, B1, B2, B3, B4, 20)   // block 1: steps 20..39

    for (int it = 0; it < 25; ++it) {
        const int base = it * 40;
        const int na = (it < 24) ? base + 40 : 920;  // clamped; stale data unused
        const int nb = (it < 24) ? base + 60 : 940;

        RUN20(A0, A1, A2, A3, A4)
        LOAD5(A0, A1, A2, A3, A4, na)
        RUN20(B0, B1, B2, B3, B4)
        LOAD5(B0, B1, B2, B3, B4, nb)
    }

#undef RUN20
#undef RUN4
#undef STEP_E
#undef STEP_O
#undef LOAD5

    keep5(we0); keep5(we1); keep5(we2); keep5(we3); keep5(we4);
    keep5(wo0); keep5(wo1); keep5(wo2); keep5(wo3); keep5(wo4);
    keep5(wie); keep5(bie); keep5(wio); keep5(bio);

    // After step 999 (odd role), lane (a,bq) holds h[bq-slice] replicated
    // over a. Mask fc weights to a==0 lanes, dot, reduce across the group.
    float dot;
    {
        const float* pf = fc_w + bq * 5;
        float f0 = oact ? pf[0] : 0.f, f1 = oact ? pf[1] : 0.f;
        float f2 = oact ? pf[2] : 0.f, f3 = oact ? pf[3] : 0.f;
        float f4 = oact ? pf[4] : 0.f;
        dot = h.v0 * f0;
        dot = __builtin_fmaf(h.v1, f1, dot);
        dot = __builtin_fmaf(h.v2, f2, dot);
        dot = __builtin_fmaf(h.v3, f3, dot);
        dot = __builtin_fmaf(h.v4, f4, dot);
    }
    dot += __shfl_xor(dot, 1, 16);
    dot += __shfl_xor(dot, 2, 16);
    dot += __shfl_xor(dot, 4, 16);
    dot += __shfl_xor(dot, 8, 16);

    if (gl == 0)
        out[b] = dot + fc_b[0];
}

extern "C" void kernel_launch(void* const* d_in, const int* in_sizes, int n_in,
                              void* d_out, int out_size, void* d_ws, size_t ws_size,
                              hipStream_t stream) {
    const float* x    = (const float*)d_in[0];
    const float* W_ih = (const float*)d_in[1];
    const float* W_hh = (const float*)d_in[2];
    const float* b_ih = (const float*)d_in[3];
    const float* b_hh = (const float*)d_in[4];
    const float* fc_w = (const float*)d_in[5];
    const float* fc_b = (const float*)d_in[6];
    float* out = (float*)d_out;

    // 4096 batches * 16 lanes = 65536 threads; 64-thread blocks -> 1024
    // single-wave blocks, one per SIMD.
    const int block = 64;
    const int grid  = (4096 * 16) / block;  // 1024 blocks
    rnn_fused_kernel<<<grid, block, 0, stream>>>(x, W_ih, W_hh, b_ih, b_hh,
                                                 fc_w, fc_b, out);
}